// Round 2
// baseline (691.400 us; speedup 1.0000x reference)
//
#include <hip/hip_runtime.h>

typedef unsigned short u16;
typedef __attribute__((ext_vector_type(8))) short bf16x8;
typedef __attribute__((ext_vector_type(4))) float f32x4;

#define H_    24
#define DH_   128
#define DIM_  3072
#define NQKV_ 9216
#define SIMG_ 2048
#define STXT_ 256
#define SQ_   2304
#define SCALE_ 0.08838834764831845f

__device__ __forceinline__ float bf2f(u16 h) {
  union { unsigned u; float f; } x; x.u = ((unsigned)h) << 16; return x.f;
}
__device__ __forceinline__ u16 f2bf(float f) {
  union { float f; unsigned u; } x; x.f = f;
  unsigned r = x.u + 0x7FFFu + ((x.u >> 16) & 1u);
  return (u16)(r >> 16);
}

__device__ __forceinline__ void gld16(const u16* g, u16* l) {
  __builtin_amdgcn_global_load_lds(
      (const __attribute__((address_space(1))) unsigned*)g,
      (__attribute__((address_space(3))) unsigned*)l, 16, 0, 0);
}

// ---------------- fp32 -> bf16 convert (vectorized) ------------------------
__global__ __launch_bounds__(256) void k_f2b(const float* __restrict__ in,
                                             u16* __restrict__ out, int n) {
  const int i = (blockIdx.x * 256 + threadIdx.x) * 4;
  if (i < n) {
    float4 v = *(const float4*)(in + i);
    ushort4 o;
    o.x = f2bf(v.x); o.y = f2bf(v.y); o.z = f2bf(v.z); o.w = f2bf(v.w);
    *(ushort4*)(out + i) = o;
  }
}

// ------- transpose+convert: in fp32 [R][C] -> out bf16 [C][R], 64x64 tiles -
__global__ __launch_bounds__(256) void k_transpose(const float* __restrict__ in,
                                                   u16* __restrict__ out,
                                                   int R, int C) {
  __shared__ __align__(16) u16 tile[64][72];
  const int t = threadIdx.x;
  const int tx = t & 15, ty = t >> 4;
  const int bc = blockIdx.x * 64, br = blockIdx.y * 64;
#pragma unroll
  for (int i = 0; i < 4; ++i) {
    const int r = ty + i * 16;
    float4 v = *(const float4*)(in + (size_t)(br + r) * C + bc + tx * 4);
    ushort4 o;
    o.x = f2bf(v.x); o.y = f2bf(v.y); o.z = f2bf(v.z); o.w = f2bf(v.w);
    *(ushort4*)&tile[r][tx * 4] = o;
  }
  __syncthreads();
#pragma unroll
  for (int i = 0; i < 4; ++i) {
    const int c = ty + i * 16;
    ushort4 v;
    v.x = tile[tx * 4 + 0][c];
    v.y = tile[tx * 4 + 1][c];
    v.z = tile[tx * 4 + 2][c];
    v.w = tile[tx * 4 + 3][c];
    *(ushort4*)(out + (size_t)(bc + c) * R + br + tx * 4) = v;
  }
}

// ---------------- GEMM: C[M][N] = A[M][K] * Bt[N][K]^T + bias --------------
// m97 structure: 128x128 tile, BK=32, 4 waves each 64x64, global_load_lds.
template <bool F32OUT>
__global__ __launch_bounds__(256) void k_gemm_bt(const u16* __restrict__ A,
                                                 const u16* __restrict__ Bt,
                                                 const float* __restrict__ bias,
                                                 void* __restrict__ Cv,
                                                 int M, int N, int K) {
  __shared__ __align__(16) u16 As[128 * 32];
  __shared__ __align__(16) u16 Bs[128 * 32];
  const int t = threadIdx.x, w = t >> 6, l = t & 63;
  const int lr = l & 15, lg = l >> 4;
  const int wr = w >> 1, wc = w & 1;
  const int bm = blockIdx.y * 128, bn = blockIdx.x * 128;

  f32x4 acc[4][4];
#pragma unroll
  for (int i = 0; i < 4; ++i)
#pragma unroll
    for (int j = 0; j < 4; ++j) acc[i][j] = (f32x4){0.f, 0.f, 0.f, 0.f};

  const u16* Ag = A + (size_t)(bm + (t >> 2)) * K + (t & 3) * 8;
  const u16* Bg = Bt + (size_t)(bn + (t >> 2)) * K + (t & 3) * 8;

  for (int k0 = 0; k0 < K; k0 += 32) {
    gld16(Ag, &As[t * 8]);
    gld16(Ag + (size_t)64 * K, &As[t * 8 + 2048]);
    gld16(Bg, &Bs[t * 8]);
    gld16(Bg + (size_t)64 * K, &Bs[t * 8 + 2048]);
    Ag += 32; Bg += 32;
    __syncthreads();
    bf16x8 af[4], bfr[4];
#pragma unroll
    for (int i = 0; i < 4; ++i)
      af[i] = *(const bf16x8*)&As[(wr * 64 + i * 16 + lr) * 32 + lg * 8];
#pragma unroll
    for (int j = 0; j < 4; ++j)
      bfr[j] = *(const bf16x8*)&Bs[(wc * 64 + j * 16 + lr) * 32 + lg * 8];
#pragma unroll
    for (int i = 0; i < 4; ++i)
#pragma unroll
      for (int j = 0; j < 4; ++j)
        acc[i][j] = __builtin_amdgcn_mfma_f32_16x16x32_bf16(af[i], bfr[j], acc[i][j], 0, 0, 0);
    __syncthreads();
  }

#pragma unroll
  for (int j = 0; j < 4; ++j) {
    const int col = bn + wc * 64 + j * 16 + lr;
    const float bv = bias[col];
#pragma unroll
    for (int i = 0; i < 4; ++i) {
      const int row = bm + wr * 64 + i * 16 + lg * 4;
#pragma unroll
      for (int r = 0; r < 4; ++r) {
        const float v = acc[i][j][r] + bv;
        if constexpr (F32OUT)
          ((float*)Cv)[(size_t)(row + r) * N + col] = v;
        else
          ((u16*)Cv)[(size_t)(row + r) * N + col] = f2bf(v);
      }
    }
  }
}

// ------------- fused RMSNorm + RoPE (non-neox) for Q,K; head-major out -----
// one wave per (s, h). Q plain; K written with global XOR swizzle d^=(s&7)<<3.
__global__ __launch_bounds__(256) void k_norm_rope(
    const u16* __restrict__ img_qkv, const u16* __restrict__ txt_qkv,
    const float* __restrict__ vid_cos, const float* __restrict__ vid_sin,
    const float* __restrict__ txt_cos, const float* __restrict__ txt_sin,
    const float* __restrict__ nq, const float* __restrict__ nk,
    const float* __restrict__ naq, const float* __restrict__ nak,
    u16* __restrict__ Qb, u16* __restrict__ Kb) {
  const int wid = blockIdx.x * 4 + (threadIdx.x >> 6);
  const int lane = threadIdx.x & 63;
  const int h = wid % H_, s = wid / H_;

  const u16* src;
  const float *cp, *sp, *qw, *kw;
  if (s < STXT_) {
    src = txt_qkv + (size_t)s * NQKV_;
    cp = txt_cos + s * 64; sp = txt_sin + s * 64;
    qw = naq; kw = nak;
  } else {
    const int si = s - STXT_;
    src = img_qkv + (size_t)si * NQKV_;
    cp = vid_cos + si * 64; sp = vid_sin + si * 64;
    qw = nq; kw = nk;
  }
  const float c = cp[lane], sn = sp[lane];
  const size_t drow = ((size_t)h * SQ_ + s) * DH_;

  // Q
  {
    ushort2 p = *(const ushort2*)(src + h * DH_ + 2 * lane);
    float x1 = bf2f(p.x), x2 = bf2f(p.y);
    float ss = x1 * x1 + x2 * x2;
#pragma unroll
    for (int m = 1; m < 64; m <<= 1) ss += __shfl_xor(ss, m);
    const float rr = rsqrtf(ss * (1.0f / 128.0f) + 1e-6f);
    const float xn1 = x1 * rr * qw[2 * lane];
    const float xn2 = x2 * rr * qw[2 * lane + 1];
    ushort2 o; o.x = f2bf(xn1 * c - xn2 * sn); o.y = f2bf(xn2 * c + xn1 * sn);
    *(ushort2*)(Qb + drow + 2 * lane) = o;
  }
  // K (swizzled)
  {
    ushort2 p = *(const ushort2*)(src + DIM_ + h * DH_ + 2 * lane);
    float x1 = bf2f(p.x), x2 = bf2f(p.y);
    float ss = x1 * x1 + x2 * x2;
#pragma unroll
    for (int m = 1; m < 64; m <<= 1) ss += __shfl_xor(ss, m);
    const float rr = rsqrtf(ss * (1.0f / 128.0f) + 1e-6f);
    const float xn1 = x1 * rr * kw[2 * lane];
    const float xn2 = x2 * rr * kw[2 * lane + 1];
    ushort2 o; o.x = f2bf(xn1 * c - xn2 * sn); o.y = f2bf(xn2 * c + xn1 * sn);
    const int col = (2 * lane) ^ ((s & 7) << 3);
    *(ushort2*)(Kb + drow + col) = o;
  }
}

// ------------- V transpose: qkv v-section -> Vt[h][d][s], swizzled ---------
__global__ __launch_bounds__(256) void k_vt(const u16* __restrict__ img_qkv,
                                            const u16* __restrict__ txt_qkv,
                                            u16* __restrict__ Vt) {
  __shared__ __align__(16) u16 tile[64][136];
  const int h = blockIdx.y, sb = blockIdx.x;
  const int t = threadIdx.x;
  {
    const int row = t >> 2, cc = (t & 3) * 32;
    const int s = sb * 64 + row;
    const u16* src = (s < STXT_) ? (txt_qkv + (size_t)s * NQKV_)
                                 : (img_qkv + (size_t)(s - STXT_) * NQKV_);
    src += 2 * DIM_ + h * DH_ + cc;
#pragma unroll
    for (int u = 0; u < 4; ++u) {
      uint4 a = *(const uint4*)(src + u * 8);
      *(uint4*)&tile[row][cc + u * 8] = a;
    }
  }
  __syncthreads();
  {
    const int w = t >> 6, lane = t & 63;
#pragma unroll 4
    for (int dd = 0; dd < 32; ++dd) {
      const int d = w * 32 + dd;
      const int m = (d & 7) << 3;
      const u16 v = tile[lane][d];
      Vt[((size_t)h * DH_ + d) * SQ_ + sb * 64 + (lane ^ m)] = v;
    }
  }
}

// ---------------- flash attention, 4 waves x 16 q-rows, KV tile 64 ---------
__global__ __launch_bounds__(256) void k_attn(const u16* __restrict__ Qb,
                                              const u16* __restrict__ Kb,
                                              const u16* __restrict__ Vt,
                                              u16* __restrict__ attnb) {
  __shared__ __align__(16) u16 Ks[64 * 128];
  __shared__ __align__(16) u16 Vs[128 * 64];
  __shared__ __align__(16) u16 Ps[4][16 * 64];
  const int t = threadIdx.x, w = t >> 6, l = t & 63;
  const int lr = l & 15, lg = l >> 4;
  const int h = blockIdx.y;
  const int qr0 = blockIdx.x * 64 + w * 16;
  const size_t head = (size_t)h * SQ_ * DH_;

  bf16x8 qf[4];
  {
    const u16* qp = Qb + head + (size_t)(qr0 + lr) * DH_ + lg * 8;
    qf[0] = *(const bf16x8*)qp;
    qf[1] = *(const bf16x8*)(qp + 32);
    qf[2] = *(const bf16x8*)(qp + 64);
    qf[3] = *(const bf16x8*)(qp + 96);
  }
  f32x4 oacc[8];
#pragma unroll
  for (int i = 0; i < 8; ++i) oacc[i] = (f32x4){0.f, 0.f, 0.f, 0.f};
  float mrow[4] = {-1e30f, -1e30f, -1e30f, -1e30f};
  float lrow[4] = {0.f, 0.f, 0.f, 0.f};

  const u16* kg0 = Kb + head + (size_t)(t >> 4) * DH_ + (t & 15) * 8;
  const u16* vg0 = Vt + head + (size_t)(t >> 3) * SQ_ + (t & 7) * 8;

  for (int kt = 0; kt < SQ_ / 64; ++kt) {
    const u16* kg = kg0 + (size_t)kt * 64 * DH_;
    const u16* vg = vg0 + kt * 64;
#pragma unroll
    for (int r = 0; r < 4; ++r) gld16(kg + (size_t)r * 16 * DH_, &Ks[t * 8 + r * 2048]);
#pragma unroll
    for (int r = 0; r < 4; ++r) gld16(vg + (size_t)r * 32 * SQ_, &Vs[t * 8 + r * 2048]);
    __syncthreads();

    // S = Q K^T (swizzled K reads)
    f32x4 sv[4];
#pragma unroll
    for (int j = 0; j < 4; ++j) {
      f32x4 a = (f32x4){0.f, 0.f, 0.f, 0.f};
      const int krow = j * 16 + lr;
      const int sm = (krow & 7) << 3;
#pragma unroll
      for (int kk = 0; kk < 4; ++kk) {
        bf16x8 kf = *(const bf16x8*)&Ks[krow * DH_ + ((kk * 32 + lg * 8) ^ sm)];
        a = __builtin_amdgcn_mfma_f32_16x16x32_bf16(qf[kk], kf, a, 0, 0, 0);
      }
      sv[j] = a;
    }

    // online softmax (rows lg*4+r, cols j*16+lr; 16-lane reductions)
    float scl[4];
#pragma unroll
    for (int r = 0; r < 4; ++r) {
      float tm = fmaxf(fmaxf(sv[0][r], sv[1][r]), fmaxf(sv[2][r], sv[3][r]));
#pragma unroll
      for (int msk = 1; msk < 16; msk <<= 1) tm = fmaxf(tm, __shfl_xor(tm, msk));
      const float mn = fmaxf(mrow[r], tm * SCALE_);
      scl[r] = __expf(mrow[r] - mn);
      mrow[r] = mn;
      const int prow = lg * 4 + r;
      const int pm = (prow & 7) << 3;
      float rs = 0.f;
#pragma unroll
      for (int j = 0; j < 4; ++j) {
        const float p = __expf(sv[j][r] * SCALE_ - mn);
        rs += p;
        Ps[w][prow * 64 + ((j * 16 + lr) ^ pm)] = f2bf(p);
      }
#pragma unroll
      for (int msk = 1; msk < 16; msk <<= 1) rs += __shfl_xor(rs, msk);
      lrow[r] = lrow[r] * scl[r] + rs;
    }
#pragma unroll
    for (int dt = 0; dt < 8; ++dt) {
      oacc[dt][0] *= scl[0]; oacc[dt][1] *= scl[1];
      oacc[dt][2] *= scl[2]; oacc[dt][3] *= scl[3];
    }

    // O += P V  (Vs is V^T per head, swizzled)
    bf16x8 pa0, pa1;
    {
      const int am = (lr & 7) << 3;
      pa0 = *(const bf16x8*)&Ps[w][lr * 64 + ((lg * 8) ^ am)];
      pa1 = *(const bf16x8*)&Ps[w][lr * 64 + ((32 + lg * 8) ^ am)];
    }
#pragma unroll
    for (int dt = 0; dt < 8; ++dt) {
      const int vrow = dt * 16 + lr;
      const int vm = (vrow & 7) << 3;
      bf16x8 v0 = *(const bf16x8*)&Vs[vrow * 64 + ((lg * 8) ^ vm)];
      bf16x8 v1 = *(const bf16x8*)&Vs[vrow * 64 + ((32 + lg * 8) ^ vm)];
      oacc[dt] = __builtin_amdgcn_mfma_f32_16x16x32_bf16(pa0, v0, oacc[dt], 0, 0, 0);
      oacc[dt] = __builtin_amdgcn_mfma_f32_16x16x32_bf16(pa1, v1, oacc[dt], 0, 0, 0);
    }
    __syncthreads();
  }

#pragma unroll
  for (int dt = 0; dt < 8; ++dt) {
#pragma unroll
    for (int r = 0; r < 4; ++r) {
      const int row = qr0 + lg * 4 + r;
      attnb[(size_t)row * DIM_ + h * DH_ + dt * 16 + lr] = f2bf(oacc[dt][r] / lrow[r]);
    }
  }
}

extern "C" void kernel_launch(void* const* d_in, const int* in_sizes, int n_in,
                              void* d_out, int out_size, void* d_ws, size_t ws_size,
                              hipStream_t stream) {
  (void)in_sizes; (void)n_in; (void)out_size; (void)ws_size;
  const float* hidden    = (const float*)d_in[0];
  const float* encoder   = (const float*)d_in[1];
  const float* vid_cos   = (const float*)d_in[2];
  const float* vid_sin   = (const float*)d_in[3];
  const float* txt_cos   = (const float*)d_in[4];
  const float* txt_sin   = (const float*)d_in[5];
  const float* w_qkv     = (const float*)d_in[6];
  const float* b_qkv     = (const float*)d_in[7];
  const float* w_add_qkv = (const float*)d_in[8];
  const float* b_add_qkv = (const float*)d_in[9];
  const float* norm_q_w  = (const float*)d_in[10];
  const float* norm_k_w  = (const float*)d_in[11];
  const float* norm_aq_w = (const float*)d_in[12];
  const float* norm_ak_w = (const float*)d_in[13];
  const float* w_out     = (const float*)d_in[14];
  const float* b_out     = (const float*)d_in[15];
  const float* w_add_out = (const float*)d_in[16];
  const float* b_add_out = (const float*)d_in[17];
  float* out = (float*)d_out;

  char* ws = (char*)d_ws;
  // region map (bytes, bf16 elements): total 198,180,864 B
  u16* wqkv_t    = (u16*)(ws + 0);            // 9216x3072 (56,623,104 B)
  u16* waddqkv_t = (u16*)(ws + 56623104);     // 9216x3072
  u16* img_qkv   = (u16*)(ws + 113246208);    // 2048x9216 (37,748,736 B)
  u16* txt_qkv   = (u16*)(ws + 150994944);    // 256x9216  (4,718,592 B)
  u16* Qb        = (u16*)(ws + 155713536);    // 24x2304x128 (14,155,776 B)
  u16* Kb        = (u16*)(ws + 169869312);
  u16* Vt        = (u16*)(ws + 184025088);    // end = 198,180,864
  u16* wout_t    = wqkv_t;                    // reuse after qkv GEMMs
  u16* waddout_t = waddqkv_t;
  u16* attnb     = img_qkv;                   // reuse after k_vt
  u16* hidden_bf = Qb;                        // consumed before Qb written
  u16* encoder_bf = Kb;                       // consumed before Kb written

  // 0) activations fp32 -> bf16
  k_f2b<<<(SIMG_ * DIM_) / 1024, 256, 0, stream>>>(hidden, hidden_bf, SIMG_ * DIM_);
  k_f2b<<<(STXT_ * DIM_) / 1024, 256, 0, stream>>>(encoder, encoder_bf, STXT_ * DIM_);
  // 1) transpose+convert qkv weights [3072][9216] -> bf16 [9216][3072]
  k_transpose<<<dim3(NQKV_ / 64, DIM_ / 64), 256, 0, stream>>>(w_qkv, wqkv_t, DIM_, NQKV_);
  k_transpose<<<dim3(NQKV_ / 64, DIM_ / 64), 256, 0, stream>>>(w_add_qkv, waddqkv_t, DIM_, NQKV_);
  // 2) qkv projections (bf16 out)
  k_gemm_bt<false><<<dim3(NQKV_ / 128, SIMG_ / 128), 256, 0, stream>>>(hidden_bf, wqkv_t, b_qkv, img_qkv, SIMG_, NQKV_, DIM_);
  k_gemm_bt<false><<<dim3(NQKV_ / 128, STXT_ / 128), 256, 0, stream>>>(encoder_bf, waddqkv_t, b_add_qkv, txt_qkv, STXT_, NQKV_, DIM_);
  // 3) rmsnorm + rope -> Q, K(swizzled) head-major (overwrites hidden_bf/encoder_bf)
  k_norm_rope<<<(SQ_ * H_) / 4, 256, 0, stream>>>(img_qkv, txt_qkv, vid_cos, vid_sin,
                                                  txt_cos, txt_sin, norm_q_w, norm_k_w,
                                                  norm_aq_w, norm_ak_w, Qb, Kb);
  // 4) V transpose -> Vt[h][d][s] (swizzled)
  k_vt<<<dim3(SQ_ / 64, H_), 256, 0, stream>>>(img_qkv, txt_qkv, Vt);
  // 5) attention -> attnb [2304][3072] bf16 (aliases img_qkv)
  k_attn<<<dim3(SQ_ / 64, H_), 256, 0, stream>>>(Qb, Kb, Vt, attnb);
  // 6) transpose+convert output-proj weights (reuse regions)
  k_transpose<<<dim3(DIM_ / 64, DIM_ / 64), 256, 0, stream>>>(w_out, wout_t, DIM_, DIM_);
  k_transpose<<<dim3(DIM_ / 64, DIM_ / 64), 256, 0, stream>>>(w_add_out, waddout_t, DIM_, DIM_);
  // 7) output projections (fp32 out): img rows 256..2303, txt rows 0..255
  k_gemm_bt<true><<<dim3(DIM_ / 128, SIMG_ / 128), 256, 0, stream>>>(attnb + (size_t)STXT_ * DIM_, wout_t, b_out, out, SIMG_, DIM_, DIM_);
  k_gemm_bt<true><<<dim3(DIM_ / 128, STXT_ / 128), 256, 0, stream>>>(attnb, waddout_t, b_add_out, out + (size_t)SIMG_ * DIM_, STXT_, DIM_, DIM_);
}

// Round 3
// 684.130 us; speedup vs baseline: 1.0106x; 1.0106x over previous
//
#include <hip/hip_runtime.h>

typedef unsigned short u16;
typedef __attribute__((ext_vector_type(8))) short bf16x8;
typedef __attribute__((ext_vector_type(4))) float f32x4;

#define H_    24
#define DH_   128
#define DIM_  3072
#define NQKV_ 9216
#define SIMG_ 2048
#define STXT_ 256
#define SQ_   2304
#define SCALE_ 0.08838834764831845f
// SCALE * log2(e): softmax in exp2 domain
#define SL_   0.1275258646912204f

__device__ __forceinline__ float bf2f(u16 h) {
  union { unsigned u; float f; } x; x.u = ((unsigned)h) << 16; return x.f;
}
__device__ __forceinline__ u16 f2bf(float f) {
  union { float f; unsigned u; } x; x.f = f;
  unsigned r = x.u + 0x7FFFu + ((x.u >> 16) & 1u);
  return (u16)(r >> 16);
}

__device__ __forceinline__ void gld16(const u16* g, u16* l) {
  __builtin_amdgcn_global_load_lds(
      (const __attribute__((address_space(1))) unsigned*)g,
      (__attribute__((address_space(3))) unsigned*)l, 16, 0, 0);
}

// ---------------- fp32 -> bf16 convert (vectorized) ------------------------
__global__ __launch_bounds__(256) void k_f2b(const float* __restrict__ in,
                                             u16* __restrict__ out, int n) {
  const int i = (blockIdx.x * 256 + threadIdx.x) * 4;
  if (i < n) {
    float4 v = *(const float4*)(in + i);
    ushort4 o;
    o.x = f2bf(v.x); o.y = f2bf(v.y); o.z = f2bf(v.z); o.w = f2bf(v.w);
    *(ushort4*)(out + i) = o;
  }
}

// ------- transpose+convert: in fp32 [R][C] -> out bf16 [C][R], 64x64 tiles -
__global__ __launch_bounds__(256) void k_transpose(const float* __restrict__ in,
                                                   u16* __restrict__ out,
                                                   int R, int C) {
  __shared__ __align__(16) u16 tile[64][72];
  const int t = threadIdx.x;
  const int tx = t & 15, ty = t >> 4;
  const int bc = blockIdx.x * 64, br = blockIdx.y * 64;
#pragma unroll
  for (int i = 0; i < 4; ++i) {
    const int r = ty + i * 16;
    float4 v = *(const float4*)(in + (size_t)(br + r) * C + bc + tx * 4);
    ushort4 o;
    o.x = f2bf(v.x); o.y = f2bf(v.y); o.z = f2bf(v.z); o.w = f2bf(v.w);
    *(ushort4*)&tile[r][tx * 4] = o;
  }
  __syncthreads();
#pragma unroll
  for (int i = 0; i < 4; ++i) {
    const int c = ty + i * 16;
    ushort4 v;
    v.x = tile[tx * 4 + 0][c];
    v.y = tile[tx * 4 + 1][c];
    v.z = tile[tx * 4 + 2][c];
    v.w = tile[tx * 4 + 3][c];
    *(ushort4*)(out + (size_t)(bc + c) * R + br + tx * 4) = v;
  }
}

// ---------------- GEMM: C[M][N] = A[M][K] * Bt[N][K]^T + bias --------------
// m97 tile + T3-min prefetch (dbuf LDS, counted vmcnt, raw barriers) + T1.
template <bool F32OUT>
__global__ __launch_bounds__(256) void k_gemm_bt(const u16* __restrict__ A,
                                                 const u16* __restrict__ Bt,
                                                 const float* __restrict__ bias,
                                                 void* __restrict__ Cv,
                                                 int M, int N, int K) {
  __shared__ __align__(16) u16 As[2][128 * 32];
  __shared__ __align__(16) u16 Bs[2][128 * 32];
  const int t = threadIdx.x, w = t >> 6, l = t & 63;
  const int lr = l & 15, lg = l >> 4;
  const int wr = w >> 1, wc = w & 1;

  // chunked bijective XCD swizzle (column-major chunks)
  const int nbm = M >> 7;
  int wg = blockIdx.x;
  if ((gridDim.x & 7) == 0) {
    const int c = gridDim.x >> 3;
    wg = (wg & 7) * c + (wg >> 3);
  }
  const int bm = (wg % nbm) * 128, bn = (wg / nbm) * 128;

  f32x4 acc[4][4];
#pragma unroll
  for (int i = 0; i < 4; ++i)
#pragma unroll
    for (int j = 0; j < 4; ++j) acc[i][j] = (f32x4){0.f, 0.f, 0.f, 0.f};

  const u16* Ag = A + (size_t)(bm + (t >> 2)) * K + (t & 3) * 8;
  const u16* Bg = Bt + (size_t)(bn + (t >> 2)) * K + (t & 3) * 8;

#define GSTAGE(buf)                                        \
  do {                                                     \
    gld16(Ag, &As[buf][t * 8]);                            \
    gld16(Ag + (size_t)64 * K, &As[buf][t * 8 + 2048]);    \
    gld16(Bg, &Bs[buf][t * 8]);                            \
    gld16(Bg + (size_t)64 * K, &Bs[buf][t * 8 + 2048]);    \
    Ag += 32; Bg += 32;                                    \
  } while (0)

  GSTAGE(0);
  const int nt = K >> 5;
  for (int tile = 0; tile < nt; ++tile) {
    const int cur = tile & 1;
    if (tile + 1 < nt) {
      GSTAGE(cur ^ 1);
      asm volatile("s_waitcnt vmcnt(4)" ::: "memory");
    } else {
      asm volatile("s_waitcnt vmcnt(0)" ::: "memory");
    }
    __builtin_amdgcn_s_barrier();
    bf16x8 af[4], bfr[4];
#pragma unroll
    for (int i = 0; i < 4; ++i)
      af[i] = *(const bf16x8*)&As[cur][(wr * 64 + i * 16 + lr) * 32 + lg * 8];
#pragma unroll
    for (int j = 0; j < 4; ++j)
      bfr[j] = *(const bf16x8*)&Bs[cur][(wc * 64 + j * 16 + lr) * 32 + lg * 8];
#pragma unroll
    for (int i = 0; i < 4; ++i)
#pragma unroll
      for (int j = 0; j < 4; ++j)
        acc[i][j] = __builtin_amdgcn_mfma_f32_16x16x32_bf16(af[i], bfr[j], acc[i][j], 0, 0, 0);
    __builtin_amdgcn_s_barrier();
  }
#undef GSTAGE

#pragma unroll
  for (int j = 0; j < 4; ++j) {
    const int col = bn + wc * 64 + j * 16 + lr;
    const float bv = bias[col];
#pragma unroll
    for (int i = 0; i < 4; ++i) {
      const int row = bm + wr * 64 + i * 16 + lg * 4;
#pragma unroll
      for (int r = 0; r < 4; ++r) {
        const float v = acc[i][j][r] + bv;
        if constexpr (F32OUT)
          ((float*)Cv)[(size_t)(row + r) * N + col] = v;
        else
          ((u16*)Cv)[(size_t)(row + r) * N + col] = f2bf(v);
      }
    }
  }
}

// ------------- fused RMSNorm + RoPE (non-neox) for Q,K; head-major out -----
__global__ __launch_bounds__(256) void k_norm_rope(
    const u16* __restrict__ img_qkv, const u16* __restrict__ txt_qkv,
    const float* __restrict__ vid_cos, const float* __restrict__ vid_sin,
    const float* __restrict__ txt_cos, const float* __restrict__ txt_sin,
    const float* __restrict__ nq, const float* __restrict__ nk,
    const float* __restrict__ naq, const float* __restrict__ nak,
    u16* __restrict__ Qb, u16* __restrict__ Kb) {
  const int wid = blockIdx.x * 4 + (threadIdx.x >> 6);
  const int lane = threadIdx.x & 63;
  const int h = wid % H_, s = wid / H_;

  const u16* src;
  const float *cp, *sp, *qw, *kw;
  if (s < STXT_) {
    src = txt_qkv + (size_t)s * NQKV_;
    cp = txt_cos + s * 64; sp = txt_sin + s * 64;
    qw = naq; kw = nak;
  } else {
    const int si = s - STXT_;
    src = img_qkv + (size_t)si * NQKV_;
    cp = vid_cos + si * 64; sp = vid_sin + si * 64;
    qw = nq; kw = nk;
  }
  const float c = cp[lane], sn = sp[lane];
  const size_t drow = ((size_t)h * SQ_ + s) * DH_;

  // Q
  {
    ushort2 p = *(const ushort2*)(src + h * DH_ + 2 * lane);
    float x1 = bf2f(p.x), x2 = bf2f(p.y);
    float ss = x1 * x1 + x2 * x2;
#pragma unroll
    for (int m = 1; m < 64; m <<= 1) ss += __shfl_xor(ss, m);
    const float rr = rsqrtf(ss * (1.0f / 128.0f) + 1e-6f);
    const float xn1 = x1 * rr * qw[2 * lane];
    const float xn2 = x2 * rr * qw[2 * lane + 1];
    ushort2 o; o.x = f2bf(xn1 * c - xn2 * sn); o.y = f2bf(xn2 * c + xn1 * sn);
    *(ushort2*)(Qb + drow + 2 * lane) = o;
  }
  // K (swizzled)
  {
    ushort2 p = *(const ushort2*)(src + DIM_ + h * DH_ + 2 * lane);
    float x1 = bf2f(p.x), x2 = bf2f(p.y);
    float ss = x1 * x1 + x2 * x2;
#pragma unroll
    for (int m = 1; m < 64; m <<= 1) ss += __shfl_xor(ss, m);
    const float rr = rsqrtf(ss * (1.0f / 128.0f) + 1e-6f);
    const float xn1 = x1 * rr * kw[2 * lane];
    const float xn2 = x2 * rr * kw[2 * lane + 1];
    ushort2 o; o.x = f2bf(xn1 * c - xn2 * sn); o.y = f2bf(xn2 * c + xn1 * sn);
    const int col = (2 * lane) ^ ((s & 7) << 3);
    *(ushort2*)(Kb + drow + col) = o;
  }
}

// ------------- V transpose: qkv v-section -> Vt[h][d][s], swizzled ---------
__global__ __launch_bounds__(256) void k_vt(const u16* __restrict__ img_qkv,
                                            const u16* __restrict__ txt_qkv,
                                            u16* __restrict__ Vt) {
  __shared__ __align__(16) u16 tile[64][136];
  const int h = blockIdx.y, sb = blockIdx.x;
  const int t = threadIdx.x;
  {
    const int row = t >> 2, cc = (t & 3) * 32;
    const int s = sb * 64 + row;
    const u16* src = (s < STXT_) ? (txt_qkv + (size_t)s * NQKV_)
                                 : (img_qkv + (size_t)(s - STXT_) * NQKV_);
    src += 2 * DIM_ + h * DH_ + cc;
#pragma unroll
    for (int u = 0; u < 4; ++u) {
      uint4 a = *(const uint4*)(src + u * 8);
      *(uint4*)&tile[row][cc + u * 8] = a;
    }
  }
  __syncthreads();
  {
    const int w = t >> 6, lane = t & 63;
#pragma unroll 4
    for (int dd = 0; dd < 32; ++dd) {
      const int d = w * 32 + dd;
      const int m = (d & 7) << 3;
      const u16 v = tile[lane][d];
      Vt[((size_t)h * DH_ + d) * SQ_ + sb * 64 + (lane ^ m)] = v;
    }
  }
}

// ------- flash attention: dbuf-K prefetch, counted vmcnt, XCD head swizzle -
__global__ __launch_bounds__(256) void k_attn(const u16* __restrict__ Qb,
                                              const u16* __restrict__ Kb,
                                              const u16* __restrict__ Vt,
                                              u16* __restrict__ attnb) {
  __shared__ __align__(16) u16 Ks[2][64 * 128];  // 32 KB
  __shared__ __align__(16) u16 Vs[128 * 64];     // 16 KB
  __shared__ __align__(16) u16 Ps[4][16 * 64];   // 8 KB
  const int t = threadIdx.x, w = t >> 6, l = t & 63;
  const int lr = l & 15, lg = l >> 4;

  // head-clustered XCD swizzle: all 36 q-blocks of a head on one XCD
  const int bid = blockIdx.x;
  const int jj = bid >> 3;
  const int h = (bid & 7) + ((jj / 36) << 3);
  const int qb = jj % 36;

  const int qr0 = qb * 64 + w * 16;
  const size_t head = (size_t)h * SQ_ * DH_;

  bf16x8 qf[4];
  {
    const u16* qp = Qb + head + (size_t)(qr0 + lr) * DH_ + lg * 8;
    qf[0] = *(const bf16x8*)qp;
    qf[1] = *(const bf16x8*)(qp + 32);
    qf[2] = *(const bf16x8*)(qp + 64);
    qf[3] = *(const bf16x8*)(qp + 96);
  }
  f32x4 oacc[8];
#pragma unroll
  for (int i = 0; i < 8; ++i) oacc[i] = (f32x4){0.f, 0.f, 0.f, 0.f};
  float mrow[4] = {-1e30f, -1e30f, -1e30f, -1e30f};
  float lrow[4] = {0.f, 0.f, 0.f, 0.f};

  const u16* kg0 = Kb + head + (size_t)(t >> 4) * DH_ + (t & 15) * 8;
  const u16* vg0 = Vt + head + (size_t)(t >> 3) * SQ_ + (t & 7) * 8;

#define KSTAGE(buf, kt)                                                        \
  do {                                                                         \
    const u16* kg_ = kg0 + (size_t)(kt) * 64 * DH_;                            \
    _Pragma("unroll")                                                          \
    for (int r_ = 0; r_ < 4; ++r_)                                             \
      gld16(kg_ + (size_t)r_ * 16 * DH_, &Ks[buf][t * 8 + r_ * 2048]);         \
  } while (0)
#define VSTAGE(kt)                                                             \
  do {                                                                         \
    const u16* vg_ = vg0 + (kt) * 64;                                          \
    _Pragma("unroll")                                                          \
    for (int r_ = 0; r_ < 4; ++r_)                                             \
      gld16(vg_ + (size_t)r_ * 32 * SQ_, &Vs[t * 8 + r_ * 2048]);              \
  } while (0)

  KSTAGE(0, 0);  // prologue: K tile 0 in flight (4 loads)
  const int nt = SQ_ / 64;
  for (int kt = 0; kt < nt; ++kt) {
    const int cur = kt & 1;
    VSTAGE(kt);  // V(kt): +4
    if (kt + 1 < nt) {
      KSTAGE(cur ^ 1, kt + 1);  // K(kt+1): +4
      asm volatile("s_waitcnt vmcnt(8)" ::: "memory");  // K(kt) landed
    } else {
      asm volatile("s_waitcnt vmcnt(4)" ::: "memory");
    }
    __builtin_amdgcn_s_barrier();

    // S = Q K^T (swizzled K reads)
    f32x4 sv[4];
#pragma unroll
    for (int j = 0; j < 4; ++j) {
      f32x4 a = (f32x4){0.f, 0.f, 0.f, 0.f};
      const int krow = j * 16 + lr;
      const int sm = (krow & 7) << 3;
#pragma unroll
      for (int kk = 0; kk < 4; ++kk) {
        bf16x8 kf = *(const bf16x8*)&Ks[cur][krow * DH_ + ((kk * 32 + lg * 8) ^ sm)];
        a = __builtin_amdgcn_mfma_f32_16x16x32_bf16(qf[kk], kf, a, 0, 0, 0);
      }
      sv[j] = a;
    }

    // online softmax in exp2 domain (rows lg*4+r, cols j*16+lr)
    float scl[4];
#pragma unroll
    for (int r = 0; r < 4; ++r) {
      float tm = fmaxf(fmaxf(sv[0][r], sv[1][r]), fmaxf(sv[2][r], sv[3][r]));
#pragma unroll
      for (int msk = 1; msk < 16; msk <<= 1) tm = fmaxf(tm, __shfl_xor(tm, msk));
      const float mn = fmaxf(mrow[r], tm * SL_);
      scl[r] = exp2f(mrow[r] - mn);
      mrow[r] = mn;
      const int prow = lg * 4 + r;
      const int pm = (prow & 7) << 3;
      float rs = 0.f;
#pragma unroll
      for (int j = 0; j < 4; ++j) {
        const float p = exp2f(fmaf(sv[j][r], SL_, -mn));
        rs += p;
        Ps[w][prow * 64 + ((j * 16 + lr) ^ pm)] = f2bf(p);
      }
#pragma unroll
      for (int msk = 1; msk < 16; msk <<= 1) rs += __shfl_xor(rs, msk);
      lrow[r] = lrow[r] * scl[r] + rs;
    }
#pragma unroll
    for (int dt = 0; dt < 8; ++dt) {
      oacc[dt][0] *= scl[0]; oacc[dt][1] *= scl[1];
      oacc[dt][2] *= scl[2]; oacc[dt][3] *= scl[3];
    }

    // wait V(kt) landed (K(kt+1) stays in flight), then barrier
    if (kt + 1 < nt) {
      asm volatile("s_waitcnt vmcnt(4)" ::: "memory");
    } else {
      asm volatile("s_waitcnt vmcnt(0)" ::: "memory");
    }
    __builtin_amdgcn_s_barrier();

    // O += P V  (Vs is V^T per head, swizzled)
    bf16x8 pa0, pa1;
    {
      const int am = (lr & 7) << 3;
      pa0 = *(const bf16x8*)&Ps[w][lr * 64 + ((lg * 8) ^ am)];
      pa1 = *(const bf16x8*)&Ps[w][lr * 64 + ((32 + lg * 8) ^ am)];
    }
#pragma unroll
    for (int dt = 0; dt < 8; ++dt) {
      const int vrow = dt * 16 + lr;
      const int vm = (vrow & 7) << 3;
      bf16x8 v0 = *(const bf16x8*)&Vs[vrow * 64 + ((lg * 8) ^ vm)];
      bf16x8 v1 = *(const bf16x8*)&Vs[vrow * 64 + ((32 + lg * 8) ^ vm)];
      oacc[dt] = __builtin_amdgcn_mfma_f32_16x16x32_bf16(pa0, v0, oacc[dt], 0, 0, 0);
      oacc[dt] = __builtin_amdgcn_mfma_f32_16x16x32_bf16(pa1, v1, oacc[dt], 0, 0, 0);
    }
    __builtin_amdgcn_s_barrier();  // protect Vs/Ks[cur^1] before next stage
  }
#undef KSTAGE
#undef VSTAGE

#pragma unroll
  for (int dt = 0; dt < 8; ++dt) {
#pragma unroll
    for (int r = 0; r < 4; ++r) {
      const int row = qr0 + lg * 4 + r;
      attnb[(size_t)row * DIM_ + h * DH_ + dt * 16 + lr] = f2bf(oacc[dt][r] / lrow[r]);
    }
  }
}

extern "C" void kernel_launch(void* const* d_in, const int* in_sizes, int n_in,
                              void* d_out, int out_size, void* d_ws, size_t ws_size,
                              hipStream_t stream) {
  (void)in_sizes; (void)n_in; (void)out_size; (void)ws_size;
  const float* hidden    = (const float*)d_in[0];
  const float* encoder   = (const float*)d_in[1];
  const float* vid_cos   = (const float*)d_in[2];
  const float* vid_sin   = (const float*)d_in[3];
  const float* txt_cos   = (const float*)d_in[4];
  const float* txt_sin   = (const float*)d_in[5];
  const float* w_qkv     = (const float*)d_in[6];
  const float* b_qkv     = (const float*)d_in[7];
  const float* w_add_qkv = (const float*)d_in[8];
  const float* b_add_qkv = (const float*)d_in[9];
  const float* norm_q_w  = (const float*)d_in[10];
  const float* norm_k_w  = (const float*)d_in[11];
  const float* norm_aq_w = (const float*)d_in[12];
  const float* norm_ak_w = (const float*)d_in[13];
  const float* w_out     = (const float*)d_in[14];
  const float* b_out     = (const float*)d_in[15];
  const float* w_add_out = (const float*)d_in[16];
  const float* b_add_out = (const float*)d_in[17];
  float* out = (float*)d_out;

  char* ws = (char*)d_ws;
  u16* wqkv_t    = (u16*)(ws + 0);            // 9216x3072 bf16
  u16* waddqkv_t = (u16*)(ws + 56623104);
  u16* img_qkv   = (u16*)(ws + 113246208);    // 2048x9216
  u16* txt_qkv   = (u16*)(ws + 150994944);    // 256x9216
  u16* Qb        = (u16*)(ws + 155713536);    // 24x2304x128
  u16* Kb        = (u16*)(ws + 169869312);
  u16* Vt        = (u16*)(ws + 184025088);    // end 198,180,864
  u16* wout_t    = wqkv_t;
  u16* waddout_t = waddqkv_t;
  u16* attnb     = img_qkv;
  u16* hidden_bf = Qb;
  u16* encoder_bf = Kb;

  k_f2b<<<(SIMG_ * DIM_) / 1024, 256, 0, stream>>>(hidden, hidden_bf, SIMG_ * DIM_);
  k_f2b<<<(STXT_ * DIM_) / 1024, 256, 0, stream>>>(encoder, encoder_bf, STXT_ * DIM_);
  k_transpose<<<dim3(NQKV_ / 64, DIM_ / 64), 256, 0, stream>>>(w_qkv, wqkv_t, DIM_, NQKV_);
  k_transpose<<<dim3(NQKV_ / 64, DIM_ / 64), 256, 0, stream>>>(w_add_qkv, waddqkv_t, DIM_, NQKV_);
  k_gemm_bt<false><<<(NQKV_ / 128) * (SIMG_ / 128), 256, 0, stream>>>(hidden_bf, wqkv_t, b_qkv, img_qkv, SIMG_, NQKV_, DIM_);
  k_gemm_bt<false><<<(NQKV_ / 128) * (STXT_ / 128), 256, 0, stream>>>(encoder_bf, waddqkv_t, b_add_qkv, txt_qkv, STXT_, NQKV_, DIM_);
  k_norm_rope<<<(SQ_ * H_) / 4, 256, 0, stream>>>(img_qkv, txt_qkv, vid_cos, vid_sin,
                                                  txt_cos, txt_sin, norm_q_w, norm_k_w,
                                                  norm_aq_w, norm_ak_w, Qb, Kb);
  k_vt<<<dim3(SQ_ / 64, H_), 256, 0, stream>>>(img_qkv, txt_qkv, Vt);
  k_attn<<<(SQ_ / 64) * H_, 256, 0, stream>>>(Qb, Kb, Vt, attnb);
  k_transpose<<<dim3(DIM_ / 64, DIM_ / 64), 256, 0, stream>>>(w_out, wout_t, DIM_, DIM_);
  k_transpose<<<dim3(DIM_ / 64, DIM_ / 64), 256, 0, stream>>>(w_add_out, waddout_t, DIM_, DIM_);
  k_gemm_bt<true><<<(DIM_ / 128) * (SIMG_ / 128), 256, 0, stream>>>(attnb + (size_t)STXT_ * DIM_, wout_t, b_out, out, SIMG_, DIM_, DIM_);
  k_gemm_bt<true><<<(DIM_ / 128) * (STXT_ / 128), 256, 0, stream>>>(attnb, waddout_t, b_add_out, out + (size_t)SIMG_ * DIM_, STXT_, DIM_, DIM_);
}

// Round 4
// 664.486 us; speedup vs baseline: 1.0405x; 1.0296x over previous
//
#include <hip/hip_runtime.h>

typedef unsigned short u16;
typedef __attribute__((ext_vector_type(8))) short bf16x8;
typedef __attribute__((ext_vector_type(4))) float f32x4;

#define H_    24
#define DH_   128
#define DIM_  3072
#define NQKV_ 9216
#define SIMG_ 2048
#define STXT_ 256
#define SQ_   2304
#define SCALE_ 0.08838834764831845f
// SCALE * log2(e): softmax in exp2 domain
#define SL_   0.1275258646912204f

__device__ __forceinline__ float bf2f(u16 h) {
  union { unsigned u; float f; } x; x.u = ((unsigned)h) << 16; return x.f;
}
__device__ __forceinline__ u16 f2bf(float f) {
  union { float f; unsigned u; } x; x.f = f;
  unsigned r = x.u + 0x7FFFu + ((x.u >> 16) & 1u);
  return (u16)(r >> 16);
}
__device__ __forceinline__ unsigned cvt_pk_bf16(float lo, float hi) {
  unsigned r;
  asm("v_cvt_pk_bf16_f32 %0, %1, %2" : "=v"(r) : "v"(lo), "v"(hi));
  return r;
}

__device__ __forceinline__ void gld16(const u16* g, u16* l) {
  __builtin_amdgcn_global_load_lds(
      (const __attribute__((address_space(1))) unsigned*)g,
      (__attribute__((address_space(3))) unsigned*)l, 16, 0, 0);
}

// ---------------- fp32 -> bf16 convert (vectorized) ------------------------
__global__ __launch_bounds__(256) void k_f2b(const float* __restrict__ in,
                                             u16* __restrict__ out, int n) {
  const int i = (blockIdx.x * 256 + threadIdx.x) * 4;
  if (i < n) {
    float4 v = *(const float4*)(in + i);
    ushort4 o;
    o.x = f2bf(v.x); o.y = f2bf(v.y); o.z = f2bf(v.z); o.w = f2bf(v.w);
    *(ushort4*)(out + i) = o;
  }
}

// ------- transpose+convert: in fp32 [R][C] -> out bf16 [C][R], 64x64 tiles -
__global__ __launch_bounds__(256) void k_transpose(const float* __restrict__ in,
                                                   u16* __restrict__ out,
                                                   int R, int C) {
  __shared__ __align__(16) u16 tile[64][72];
  const int t = threadIdx.x;
  const int tx = t & 15, ty = t >> 4;
  const int bc = blockIdx.x * 64, br = blockIdx.y * 64;
#pragma unroll
  for (int i = 0; i < 4; ++i) {
    const int r = ty + i * 16;
    float4 v = *(const float4*)(in + (size_t)(br + r) * C + bc + tx * 4);
    ushort4 o;
    o.x = f2bf(v.x); o.y = f2bf(v.y); o.z = f2bf(v.z); o.w = f2bf(v.w);
    *(ushort4*)&tile[r][tx * 4] = o;
  }
  __syncthreads();
#pragma unroll
  for (int i = 0; i < 4; ++i) {
    const int c = ty + i * 16;
    ushort4 v;
    v.x = tile[tx * 4 + 0][c];
    v.y = tile[tx * 4 + 1][c];
    v.z = tile[tx * 4 + 2][c];
    v.w = tile[tx * 4 + 3][c];
    *(ushort4*)(out + (size_t)(bc + c) * R + br + tx * 4) = v;
  }
}

// ---------------- GEMM: C[M][N] = A[M][K] * Bt[N][K]^T + bias --------------
template <bool F32OUT>
__global__ __launch_bounds__(256) void k_gemm_bt(const u16* __restrict__ A,
                                                 const u16* __restrict__ Bt,
                                                 const float* __restrict__ bias,
                                                 void* __restrict__ Cv,
                                                 int M, int N, int K) {
  __shared__ __align__(16) u16 As[2][128 * 32];
  __shared__ __align__(16) u16 Bs[2][128 * 32];
  const int t = threadIdx.x, w = t >> 6, l = t & 63;
  const int lr = l & 15, lg = l >> 4;
  const int wr = w >> 1, wc = w & 1;

  // chunked bijective XCD swizzle (column-major chunks)
  const int nbm = M >> 7;
  int wg = blockIdx.x;
  if ((gridDim.x & 7) == 0) {
    const int c = gridDim.x >> 3;
    wg = (wg & 7) * c + (wg >> 3);
  }
  const int bm = (wg % nbm) * 128, bn = (wg / nbm) * 128;

  f32x4 acc[4][4];
#pragma unroll
  for (int i = 0; i < 4; ++i)
#pragma unroll
    for (int j = 0; j < 4; ++j) acc[i][j] = (f32x4){0.f, 0.f, 0.f, 0.f};

  const u16* Ag = A + (size_t)(bm + (t >> 2)) * K + (t & 3) * 8;
  const u16* Bg = Bt + (size_t)(bn + (t >> 2)) * K + (t & 3) * 8;

#define GSTAGE(buf)                                        \
  do {                                                     \
    gld16(Ag, &As[buf][t * 8]);                            \
    gld16(Ag + (size_t)64 * K, &As[buf][t * 8 + 2048]);    \
    gld16(Bg, &Bs[buf][t * 8]);                            \
    gld16(Bg + (size_t)64 * K, &Bs[buf][t * 8 + 2048]);    \
    Ag += 32; Bg += 32;                                    \
  } while (0)

  GSTAGE(0);
  const int nt = K >> 5;
  for (int tile = 0; tile < nt; ++tile) {
    const int cur = tile & 1;
    if (tile + 1 < nt) {
      GSTAGE(cur ^ 1);
      asm volatile("s_waitcnt vmcnt(4)" ::: "memory");
    } else {
      asm volatile("s_waitcnt vmcnt(0)" ::: "memory");
    }
    __builtin_amdgcn_s_barrier();
    bf16x8 af[4], bfr[4];
#pragma unroll
    for (int i = 0; i < 4; ++i)
      af[i] = *(const bf16x8*)&As[cur][(wr * 64 + i * 16 + lr) * 32 + lg * 8];
#pragma unroll
    for (int j = 0; j < 4; ++j)
      bfr[j] = *(const bf16x8*)&Bs[cur][(wc * 64 + j * 16 + lr) * 32 + lg * 8];
#pragma unroll
    for (int i = 0; i < 4; ++i)
#pragma unroll
      for (int j = 0; j < 4; ++j)
        acc[i][j] = __builtin_amdgcn_mfma_f32_16x16x32_bf16(af[i], bfr[j], acc[i][j], 0, 0, 0);
    __builtin_amdgcn_s_barrier();
  }
#undef GSTAGE

#pragma unroll
  for (int j = 0; j < 4; ++j) {
    const int col = bn + wc * 64 + j * 16 + lr;
    const float bv = bias[col];
#pragma unroll
    for (int i = 0; i < 4; ++i) {
      const int row = bm + wr * 64 + i * 16 + lg * 4;
#pragma unroll
      for (int r = 0; r < 4; ++r) {
        const float v = acc[i][j][r] + bv;
        if constexpr (F32OUT)
          ((float*)Cv)[(size_t)(row + r) * N + col] = v;
        else
          ((u16*)Cv)[(size_t)(row + r) * N + col] = f2bf(v);
      }
    }
  }
}

// ------------- fused RMSNorm + RoPE (non-neox) for Q,K; head-major out -----
__global__ __launch_bounds__(256) void k_norm_rope(
    const u16* __restrict__ img_qkv, const u16* __restrict__ txt_qkv,
    const float* __restrict__ vid_cos, const float* __restrict__ vid_sin,
    const float* __restrict__ txt_cos, const float* __restrict__ txt_sin,
    const float* __restrict__ nq, const float* __restrict__ nk,
    const float* __restrict__ naq, const float* __restrict__ nak,
    u16* __restrict__ Qb, u16* __restrict__ Kb) {
  const int wid = blockIdx.x * 4 + (threadIdx.x >> 6);
  const int lane = threadIdx.x & 63;
  const int h = wid % H_, s = wid / H_;

  const u16* src;
  const float *cp, *sp, *qw, *kw;
  if (s < STXT_) {
    src = txt_qkv + (size_t)s * NQKV_;
    cp = txt_cos + s * 64; sp = txt_sin + s * 64;
    qw = naq; kw = nak;
  } else {
    const int si = s - STXT_;
    src = img_qkv + (size_t)si * NQKV_;
    cp = vid_cos + si * 64; sp = vid_sin + si * 64;
    qw = nq; kw = nk;
  }
  const float c = cp[lane], sn = sp[lane];
  const size_t drow = ((size_t)h * SQ_ + s) * DH_;

  // Q
  {
    ushort2 p = *(const ushort2*)(src + h * DH_ + 2 * lane);
    float x1 = bf2f(p.x), x2 = bf2f(p.y);
    float ss = x1 * x1 + x2 * x2;
#pragma unroll
    for (int m = 1; m < 64; m <<= 1) ss += __shfl_xor(ss, m);
    const float rr = rsqrtf(ss * (1.0f / 128.0f) + 1e-6f);
    const float xn1 = x1 * rr * qw[2 * lane];
    const float xn2 = x2 * rr * qw[2 * lane + 1];
    ushort2 o; o.x = f2bf(xn1 * c - xn2 * sn); o.y = f2bf(xn2 * c + xn1 * sn);
    *(ushort2*)(Qb + drow + 2 * lane) = o;
  }
  // K (swizzled within 128 cols: col ^= (s&7)<<3)
  {
    ushort2 p = *(const ushort2*)(src + DIM_ + h * DH_ + 2 * lane);
    float x1 = bf2f(p.x), x2 = bf2f(p.y);
    float ss = x1 * x1 + x2 * x2;
#pragma unroll
    for (int m = 1; m < 64; m <<= 1) ss += __shfl_xor(ss, m);
    const float rr = rsqrtf(ss * (1.0f / 128.0f) + 1e-6f);
    const float xn1 = x1 * rr * kw[2 * lane];
    const float xn2 = x2 * rr * kw[2 * lane + 1];
    ushort2 o; o.x = f2bf(xn1 * c - xn2 * sn); o.y = f2bf(xn2 * c + xn1 * sn);
    const int col = (2 * lane) ^ ((s & 7) << 3);
    *(ushort2*)(Kb + drow + col) = o;
  }
}

// --- V transpose: qkv v-section -> Vt[h][d][s], s swizzled within 32-chunk -
__global__ __launch_bounds__(256) void k_vt(const u16* __restrict__ img_qkv,
                                            const u16* __restrict__ txt_qkv,
                                            u16* __restrict__ Vt) {
  __shared__ __align__(16) u16 tile[64][136];
  const int h = blockIdx.y, sb = blockIdx.x;
  const int t = threadIdx.x;
  {
    const int row = t >> 2, cc = (t & 3) * 32;
    const int s = sb * 64 + row;
    const u16* src = (s < STXT_) ? (txt_qkv + (size_t)s * NQKV_)
                                 : (img_qkv + (size_t)(s - STXT_) * NQKV_);
    src += 2 * DIM_ + h * DH_ + cc;
#pragma unroll
    for (int u = 0; u < 4; ++u) {
      uint4 a = *(const uint4*)(src + u * 8);
      *(uint4*)&tile[row][cc + u * 8] = a;
    }
  }
  __syncthreads();
  {
    const int w = t >> 6, lane = t & 63;
#pragma unroll 4
    for (int dd = 0; dd < 32; ++dd) {
      const int d = w * 32 + dd;
      const int m = (d & 3) << 3;  // swizzle within 32-wide chunk
      const u16 v = tile[lane][d];
      Vt[((size_t)h * DH_ + d) * SQ_ + sb * 64 + (lane ^ m)] = v;
    }
  }
}

// --- flash attention: swapped-QK^T, in-register softmax, KVBLK=32 dbuf -----
__global__ __launch_bounds__(256) void k_attn(const u16* __restrict__ Qb,
                                              const u16* __restrict__ Kb,
                                              const u16* __restrict__ Vt,
                                              u16* __restrict__ attnb) {
  __shared__ __align__(16) u16 Ks[2][32 * 128];  // 16 KB
  __shared__ __align__(16) u16 Vs[2][128 * 32];  // 16 KB
  __shared__ __align__(16) u16 Ps[4][16 * 32];   // 4 KB
  const int t = threadIdx.x, w = t >> 6, l = t & 63;
  const int lr = l & 15, lg = l >> 4;

  // head-clustered XCD swizzle: all 36 q-blocks of a head on one XCD
  const int bid = blockIdx.x;
  const int jj = bid >> 3;
  const int h = (bid & 7) + ((jj / 36) << 3);
  const int qb = jj % 36;

  const int qr0 = qb * 64 + w * 16;
  const size_t head = (size_t)h * SQ_ * DH_;

  // Q as B-operand fragments (q = lane&15, dh in regs) — same addresses as A-frag
  bf16x8 qf[4];
  {
    const u16* qp = Qb + head + (size_t)(qr0 + lr) * DH_ + lg * 8;
    qf[0] = *(const bf16x8*)qp;
    qf[1] = *(const bf16x8*)(qp + 32);
    qf[2] = *(const bf16x8*)(qp + 64);
    qf[3] = *(const bf16x8*)(qp + 96);
  }
  f32x4 oacc[8];  // O^T frags: col=q=lr, rows d = dt*16 + lg*4 + r
#pragma unroll
  for (int i = 0; i < 8; ++i) oacc[i] = (f32x4){0.f, 0.f, 0.f, 0.f};
  float mrun = -1e30f, lrun = 0.f;  // scalar per lane (q-row replicated x4)

  const u16* kg0 = Kb + head + (size_t)(t >> 4) * DH_ + (t & 15) * 8;
  const u16* vg0 = Vt + head + (size_t)(t >> 2) * SQ_ + (t & 3) * 8;

#define STAGE(buf, kt)                                                  \
  do {                                                                  \
    const u16* kg_ = kg0 + (size_t)(kt) * 32 * DH_;                     \
    gld16(kg_, &Ks[buf][t * 8]);                                        \
    gld16(kg_ + (size_t)16 * DH_, &Ks[buf][t * 8 + 2048]);              \
    const u16* vg_ = vg0 + (kt) * 32;                                   \
    gld16(vg_, &Vs[buf][t * 8]);                                        \
    gld16(vg_ + (size_t)64 * SQ_, &Vs[buf][t * 8 + 2048]);              \
  } while (0)

  STAGE(0, 0);
  const int nt = SQ_ / 32;  // 72
  for (int kt = 0; kt < nt; ++kt) {
    const int cur = kt & 1;
    if (kt + 1 < nt) {
      STAGE(cur ^ 1, kt + 1);
      asm volatile("s_waitcnt vmcnt(4)" ::: "memory");
    } else {
      asm volatile("s_waitcnt vmcnt(0)" ::: "memory");
    }
    __builtin_amdgcn_s_barrier();

    // S^T = K Q^T : D[kpos][q], q = lr, kpos = j*16 + lg*4 + r
    f32x4 sv[2];
#pragma unroll
    for (int j = 0; j < 2; ++j) {
      f32x4 a = (f32x4){0.f, 0.f, 0.f, 0.f};
      const int krow = j * 16 + lr;
      const int sm = (krow & 7) << 3;
#pragma unroll
      for (int kk = 0; kk < 4; ++kk) {
        bf16x8 kf = *(const bf16x8*)&Ks[cur][krow * DH_ + ((kk * 32 + lg * 8) ^ sm)];
        a = __builtin_amdgcn_mfma_f32_16x16x32_bf16(kf, qf[kk], a, 0, 0, 0);
      }
      sv[j] = a;
    }

    // in-register online softmax (one q-row per lane; 2 shuffles total)
    float tm = fmaxf(fmaxf(fmaxf(sv[0][0], sv[0][1]), fmaxf(sv[0][2], sv[0][3])),
                     fmaxf(fmaxf(sv[1][0], sv[1][1]), fmaxf(sv[1][2], sv[1][3])));
    tm = fmaxf(tm, __shfl_xor(tm, 16));
    tm = fmaxf(tm, __shfl_xor(tm, 32));
    const float sc = tm * SL_;
    if (!__all(sc - mrun <= 8.0f)) {  // defer-max (T13)
      const float mn = fmaxf(mrun, sc);
      const float scl = exp2f(mrun - mn);
      mrun = mn;
      lrun *= scl;
#pragma unroll
      for (int dt = 0; dt < 8; ++dt) {
        oacc[dt][0] *= scl; oacc[dt][1] *= scl;
        oacc[dt][2] *= scl; oacc[dt][3] *= scl;
      }
    }
    float p[2][4];
    float rs = 0.f;
#pragma unroll
    for (int j = 0; j < 2; ++j)
#pragma unroll
      for (int r = 0; r < 4; ++r) {
        p[j][r] = exp2f(fmaf(sv[j][r], SL_, -mrun));
        rs += p[j][r];
      }
    rs += __shfl_xor(rs, 16);
    rs += __shfl_xor(rs, 32);
    lrun += rs;

    // pack P -> Ps in B-frag layout (kpos swizzled by lr within 32)
    {
      const int swz = (lr & 3) << 3;
      uint2 w0, w1;
      w0.x = cvt_pk_bf16(p[0][0], p[0][1]);
      w0.y = cvt_pk_bf16(p[0][2], p[0][3]);
      w1.x = cvt_pk_bf16(p[1][0], p[1][1]);
      w1.y = cvt_pk_bf16(p[1][2], p[1][3]);
      *(uint2*)&Ps[w][lr * 32 + ((lg * 4) ^ swz)] = w0;
      *(uint2*)&Ps[w][lr * 32 + ((16 + lg * 4) ^ swz)] = w1;
    }
    asm volatile("s_waitcnt lgkmcnt(0)" ::: "memory");
    const bf16x8 pb = *(const bf16x8*)&Ps[w][lr * 32 + 8 * (lg ^ (lr & 3))];

    // O^T += V^T P^T
#pragma unroll
    for (int dt = 0; dt < 8; ++dt) {
      const int d = dt * 16 + lr;
      bf16x8 va = *(const bf16x8*)&Vs[cur][d * 32 + ((lg * 8) ^ ((d & 3) << 3))];
      oacc[dt] = __builtin_amdgcn_mfma_f32_16x16x32_bf16(va, pb, oacc[dt], 0, 0, 0);
    }
    __builtin_amdgcn_s_barrier();
  }
#undef STAGE

  const float rinv = 1.0f / lrun;
#pragma unroll
  for (int dt = 0; dt < 8; ++dt) {
    ushort4 o;
    o.x = f2bf(oacc[dt][0] * rinv);
    o.y = f2bf(oacc[dt][1] * rinv);
    o.z = f2bf(oacc[dt][2] * rinv);
    o.w = f2bf(oacc[dt][3] * rinv);
    *(ushort4*)(attnb + (size_t)(qr0 + lr) * DIM_ + h * DH_ + dt * 16 + lg * 4) = o;
  }
}

extern "C" void kernel_launch(void* const* d_in, const int* in_sizes, int n_in,
                              void* d_out, int out_size, void* d_ws, size_t ws_size,
                              hipStream_t stream) {
  (void)in_sizes; (void)n_in; (void)out_size; (void)ws_size;
  const float* hidden    = (const float*)d_in[0];
  const float* encoder   = (const float*)d_in[1];
  const float* vid_cos   = (const float*)d_in[2];
  const float* vid_sin   = (const float*)d_in[3];
  const float* txt_cos   = (const float*)d_in[4];
  const float* txt_sin   = (const float*)d_in[5];
  const float* w_qkv     = (const float*)d_in[6];
  const float* b_qkv     = (const float*)d_in[7];
  const float* w_add_qkv = (const float*)d_in[8];
  const float* b_add_qkv = (const float*)d_in[9];
  const float* norm_q_w  = (const float*)d_in[10];
  const float* norm_k_w  = (const float*)d_in[11];
  const float* norm_aq_w = (const float*)d_in[12];
  const float* norm_ak_w = (const float*)d_in[13];
  const float* w_out     = (const float*)d_in[14];
  const float* b_out     = (const float*)d_in[15];
  const float* w_add_out = (const float*)d_in[16];
  const float* b_add_out = (const float*)d_in[17];
  float* out = (float*)d_out;

  char* ws = (char*)d_ws;
  u16* wqkv_t    = (u16*)(ws + 0);            // 9216x3072 bf16
  u16* waddqkv_t = (u16*)(ws + 56623104);
  u16* img_qkv   = (u16*)(ws + 113246208);    // 2048x9216
  u16* txt_qkv   = (u16*)(ws + 150994944);    // 256x9216
  u16* Qb        = (u16*)(ws + 155713536);    // 24x2304x128
  u16* Kb        = (u16*)(ws + 169869312);
  u16* Vt        = (u16*)(ws + 184025088);    // end 198,180,864
  u16* wout_t    = wqkv_t;
  u16* waddout_t = waddqkv_t;
  u16* attnb     = img_qkv;
  u16* hidden_bf = Qb;
  u16* encoder_bf = Kb;

  k_f2b<<<(SIMG_ * DIM_) / 1024, 256, 0, stream>>>(hidden, hidden_bf, SIMG_ * DIM_);
  k_f2b<<<(STXT_ * DIM_) / 1024, 256, 0, stream>>>(encoder, encoder_bf, STXT_ * DIM_);
  k_transpose<<<dim3(NQKV_ / 64, DIM_ / 64), 256, 0, stream>>>(w_qkv, wqkv_t, DIM_, NQKV_);
  k_transpose<<<dim3(NQKV_ / 64, DIM_ / 64), 256, 0, stream>>>(w_add_qkv, waddqkv_t, DIM_, NQKV_);
  k_gemm_bt<false><<<(NQKV_ / 128) * (SIMG_ / 128), 256, 0, stream>>>(hidden_bf, wqkv_t, b_qkv, img_qkv, SIMG_, NQKV_, DIM_);
  k_gemm_bt<false><<<(NQKV_ / 128) * (STXT_ / 128), 256, 0, stream>>>(encoder_bf, waddqkv_t, b_add_qkv, txt_qkv, STXT_, NQKV_, DIM_);
  k_norm_rope<<<(SQ_ * H_) / 4, 256, 0, stream>>>(img_qkv, txt_qkv, vid_cos, vid_sin,
                                                  txt_cos, txt_sin, norm_q_w, norm_k_w,
                                                  norm_aq_w, norm_ak_w, Qb, Kb);
  k_vt<<<dim3(SQ_ / 64, H_), 256, 0, stream>>>(img_qkv, txt_qkv, Vt);
  k_attn<<<(SQ_ / 64) * H_, 256, 0, stream>>>(Qb, Kb, Vt, attnb);
  k_transpose<<<dim3(DIM_ / 64, DIM_ / 64), 256, 0, stream>>>(w_out, wout_t, DIM_, DIM_);
  k_transpose<<<dim3(DIM_ / 64, DIM_ / 64), 256, 0, stream>>>(w_add_out, waddout_t, DIM_, DIM_);
  k_gemm_bt<true><<<(DIM_ / 128) * (SIMG_ / 128), 256, 0, stream>>>(attnb + (size_t)STXT_ * DIM_, wout_t, b_out, out, SIMG_, DIM_, DIM_);
  k_gemm_bt<true><<<(DIM_ / 128) * (STXT_ / 128), 256, 0, stream>>>(attnb, waddout_t, b_add_out, out + (size_t)SIMG_ * DIM_, STXT_, DIM_, DIM_);
}

// Round 5
// 554.524 us; speedup vs baseline: 1.2468x; 1.1983x over previous
//
#include <hip/hip_runtime.h>

typedef unsigned short u16;
typedef __attribute__((ext_vector_type(8))) short bf16x8;
typedef __attribute__((ext_vector_type(4))) float f32x4;
typedef __attribute__((ext_vector_type(16))) float f32x16;

#define H_    24
#define DH_   128
#define DIM_  3072
#define NQKV_ 9216
#define SIMG_ 2048
#define STXT_ 256
#define SQ_   2304
#define SCALE_ 0.08838834764831845f
// SCALE * log2(e): softmax in exp2 domain
#define SL_   0.1275258646912204f

__device__ __forceinline__ float bf2f(u16 h) {
  union { unsigned u; float f; } x; x.u = ((unsigned)h) << 16; return x.f;
}
__device__ __forceinline__ u16 f2bf(float f) {
  union { float f; unsigned u; } x; x.f = f;
  unsigned r = x.u + 0x7FFFu + ((x.u >> 16) & 1u);
  return (u16)(r >> 16);
}
__device__ __forceinline__ unsigned cvt_pk_bf16(float lo, float hi) {
  unsigned r;
  asm("v_cvt_pk_bf16_f32 %0, %1, %2" : "=v"(r) : "v"(lo), "v"(hi));
  return r;
}

__device__ __forceinline__ void gld16(const u16* g, u16* l) {
  __builtin_amdgcn_global_load_lds(
      (const __attribute__((address_space(1))) unsigned*)g,
      (__attribute__((address_space(3))) unsigned*)l, 16, 0, 0);
}

// ---------------- fp32 -> bf16 convert (vectorized) ------------------------
__global__ __launch_bounds__(256) void k_f2b(const float* __restrict__ in,
                                             u16* __restrict__ out, int n) {
  const int i = (blockIdx.x * 256 + threadIdx.x) * 4;
  if (i < n) {
    float4 v = *(const float4*)(in + i);
    ushort4 o;
    o.x = f2bf(v.x); o.y = f2bf(v.y); o.z = f2bf(v.z); o.w = f2bf(v.w);
    *(ushort4*)(out + i) = o;
  }
}

// ------- transpose+convert: in fp32 [R][C] -> out bf16 [C][R], 64x64 tiles -
__global__ __launch_bounds__(256) void k_transpose(const float* __restrict__ in,
                                                   u16* __restrict__ out,
                                                   int R, int C) {
  __shared__ __align__(16) u16 tile[64][72];
  const int t = threadIdx.x;
  const int tx = t & 15, ty = t >> 4;
  const int bc = blockIdx.x * 64, br = blockIdx.y * 64;
#pragma unroll
  for (int i = 0; i < 4; ++i) {
    const int r = ty + i * 16;
    float4 v = *(const float4*)(in + (size_t)(br + r) * C + bc + tx * 4);
    ushort4 o;
    o.x = f2bf(v.x); o.y = f2bf(v.y); o.z = f2bf(v.z); o.w = f2bf(v.w);
    *(ushort4*)&tile[r][tx * 4] = o;
  }
  __syncthreads();
#pragma unroll
  for (int i = 0; i < 4; ++i) {
    const int c = ty + i * 16;
    ushort4 v;
    v.x = tile[tx * 4 + 0][c];
    v.y = tile[tx * 4 + 1][c];
    v.z = tile[tx * 4 + 2][c];
    v.w = tile[tx * 4 + 3][c];
    *(ushort4*)(out + (size_t)(bc + c) * R + br + tx * 4) = v;
  }
}

// ---------------- GEMM: C[M][N] = A[M][K] * Bt[N][K]^T + bias --------------
template <bool F32OUT>
__global__ __launch_bounds__(256) void k_gemm_bt(const u16* __restrict__ A,
                                                 const u16* __restrict__ Bt,
                                                 const float* __restrict__ bias,
                                                 void* __restrict__ Cv,
                                                 int M, int N, int K) {
  __shared__ __align__(16) u16 As[2][128 * 32];
  __shared__ __align__(16) u16 Bs[2][128 * 32];
  const int t = threadIdx.x, w = t >> 6, l = t & 63;
  const int lr = l & 15, lg = l >> 4;
  const int wr = w >> 1, wc = w & 1;

  // chunked bijective XCD swizzle (column-major chunks)
  const int nbm = M >> 7;
  int wg = blockIdx.x;
  if ((gridDim.x & 7) == 0) {
    const int c = gridDim.x >> 3;
    wg = (wg & 7) * c + (wg >> 3);
  }
  const int bm = (wg % nbm) * 128, bn = (wg / nbm) * 128;

  f32x4 acc[4][4];
#pragma unroll
  for (int i = 0; i < 4; ++i)
#pragma unroll
    for (int j = 0; j < 4; ++j) acc[i][j] = (f32x4){0.f, 0.f, 0.f, 0.f};

  const u16* Ag = A + (size_t)(bm + (t >> 2)) * K + (t & 3) * 8;
  const u16* Bg = Bt + (size_t)(bn + (t >> 2)) * K + (t & 3) * 8;

#define GSTAGE(buf)                                        \
  do {                                                     \
    gld16(Ag, &As[buf][t * 8]);                            \
    gld16(Ag + (size_t)64 * K, &As[buf][t * 8 + 2048]);    \
    gld16(Bg, &Bs[buf][t * 8]);                            \
    gld16(Bg + (size_t)64 * K, &Bs[buf][t * 8 + 2048]);    \
    Ag += 32; Bg += 32;                                    \
  } while (0)

  GSTAGE(0);
  const int nt = K >> 5;
  for (int tile = 0; tile < nt; ++tile) {
    const int cur = tile & 1;
    if (tile + 1 < nt) {
      GSTAGE(cur ^ 1);
      asm volatile("s_waitcnt vmcnt(4)" ::: "memory");
    } else {
      asm volatile("s_waitcnt vmcnt(0)" ::: "memory");
    }
    __builtin_amdgcn_s_barrier();
    bf16x8 af[4], bfr[4];
#pragma unroll
    for (int i = 0; i < 4; ++i)
      af[i] = *(const bf16x8*)&As[cur][(wr * 64 + i * 16 + lr) * 32 + lg * 8];
#pragma unroll
    for (int j = 0; j < 4; ++j)
      bfr[j] = *(const bf16x8*)&Bs[cur][(wc * 64 + j * 16 + lr) * 32 + lg * 8];
#pragma unroll
    for (int i = 0; i < 4; ++i)
#pragma unroll
      for (int j = 0; j < 4; ++j)
        acc[i][j] = __builtin_amdgcn_mfma_f32_16x16x32_bf16(af[i], bfr[j], acc[i][j], 0, 0, 0);
    __builtin_amdgcn_s_barrier();
  }
#undef GSTAGE

#pragma unroll
  for (int j = 0; j < 4; ++j) {
    const int col = bn + wc * 64 + j * 16 + lr;
    const float bv = bias[col];
#pragma unroll
    for (int i = 0; i < 4; ++i) {
      const int row = bm + wr * 64 + i * 16 + lg * 4;
#pragma unroll
      for (int r = 0; r < 4; ++r) {
        const float v = acc[i][j][r] + bv;
        if constexpr (F32OUT)
          ((float*)Cv)[(size_t)(row + r) * N + col] = v;
        else
          ((u16*)Cv)[(size_t)(row + r) * N + col] = f2bf(v);
      }
    }
  }
}

// ------------- fused RMSNorm + RoPE (non-neox) for Q,K; head-major out -----
__global__ __launch_bounds__(256) void k_norm_rope(
    const u16* __restrict__ img_qkv, const u16* __restrict__ txt_qkv,
    const float* __restrict__ vid_cos, const float* __restrict__ vid_sin,
    const float* __restrict__ txt_cos, const float* __restrict__ txt_sin,
    const float* __restrict__ nq, const float* __restrict__ nk,
    const float* __restrict__ naq, const float* __restrict__ nak,
    u16* __restrict__ Qb, u16* __restrict__ Kb) {
  const int wid = blockIdx.x * 4 + (threadIdx.x >> 6);
  const int lane = threadIdx.x & 63;
  const int h = wid % H_, s = wid / H_;

  const u16* src;
  const float *cp, *sp, *qw, *kw;
  if (s < STXT_) {
    src = txt_qkv + (size_t)s * NQKV_;
    cp = txt_cos + s * 64; sp = txt_sin + s * 64;
    qw = naq; kw = nak;
  } else {
    const int si = s - STXT_;
    src = img_qkv + (size_t)si * NQKV_;
    cp = vid_cos + si * 64; sp = vid_sin + si * 64;
    qw = nq; kw = nk;
  }
  const float c = cp[lane], sn = sp[lane];
  const size_t drow = ((size_t)h * SQ_ + s) * DH_;

  // Q
  {
    ushort2 p = *(const ushort2*)(src + h * DH_ + 2 * lane);
    float x1 = bf2f(p.x), x2 = bf2f(p.y);
    float ss = x1 * x1 + x2 * x2;
#pragma unroll
    for (int m = 1; m < 64; m <<= 1) ss += __shfl_xor(ss, m);
    const float rr = rsqrtf(ss * (1.0f / 128.0f) + 1e-6f);
    const float xn1 = x1 * rr * qw[2 * lane];
    const float xn2 = x2 * rr * qw[2 * lane + 1];
    ushort2 o; o.x = f2bf(xn1 * c - xn2 * sn); o.y = f2bf(xn2 * c + xn1 * sn);
    *(ushort2*)(Qb + drow + 2 * lane) = o;
  }
  // K (swizzled within 128 cols: col ^= (s&7)<<3)
  {
    ushort2 p = *(const ushort2*)(src + DIM_ + h * DH_ + 2 * lane);
    float x1 = bf2f(p.x), x2 = bf2f(p.y);
    float ss = x1 * x1 + x2 * x2;
#pragma unroll
    for (int m = 1; m < 64; m <<= 1) ss += __shfl_xor(ss, m);
    const float rr = rsqrtf(ss * (1.0f / 128.0f) + 1e-6f);
    const float xn1 = x1 * rr * kw[2 * lane];
    const float xn2 = x2 * rr * kw[2 * lane + 1];
    ushort2 o; o.x = f2bf(xn1 * c - xn2 * sn); o.y = f2bf(xn2 * c + xn1 * sn);
    const int col = (2 * lane) ^ ((s & 7) << 3);
    *(ushort2*)(Kb + drow + col) = o;
  }
}

// --- V transpose: qkv v-section -> Vt[h][d][s], s swizzled (d&7)<<3 in 64 --
__global__ __launch_bounds__(256) void k_vt(const u16* __restrict__ img_qkv,
                                            const u16* __restrict__ txt_qkv,
                                            u16* __restrict__ Vt) {
  __shared__ __align__(16) u16 tile[64][136];
  const int h = blockIdx.y, sb = blockIdx.x;
  const int t = threadIdx.x;
  {
    const int row = t >> 2, cc = (t & 3) * 32;
    const int s = sb * 64 + row;
    const u16* src = (s < STXT_) ? (txt_qkv + (size_t)s * NQKV_)
                                 : (img_qkv + (size_t)(s - STXT_) * NQKV_);
    src += 2 * DIM_ + h * DH_ + cc;
#pragma unroll
    for (int u = 0; u < 4; ++u) {
      uint4 a = *(const uint4*)(src + u * 8);
      *(uint4*)&tile[row][cc + u * 8] = a;
    }
  }
  __syncthreads();
  {
    const int w = t >> 6, lane = t & 63;
#pragma unroll 4
    for (int dd = 0; dd < 32; ++dd) {
      const int d = w * 32 + dd;
      const int m = (d & 7) << 3;  // swizzle within 64-wide s-group
      const u16 v = tile[lane][d];
      Vt[((size_t)h * DH_ + d) * SQ_ + sb * 64 + (lane ^ m)] = v;
    }
  }
}

// --- flash attention: 32x32 swapped-QK^T, in-reg P via permlane32_swap -----
// 4 waves x 32 q-rows, KVBLK=64 double-buffered (64KB LDS), 2 barriers/tile.
__global__ __launch_bounds__(256, 2) void k_attn(const u16* __restrict__ Qb,
                                                 const u16* __restrict__ Kb,
                                                 const u16* __restrict__ Vt,
                                                 u16* __restrict__ attnb) {
  __shared__ __align__(16) u16 Ks[2][64 * 128];  // 32 KB
  __shared__ __align__(16) u16 Vs[2][128 * 64];  // 32 KB
  const int t = threadIdx.x, w = t >> 6, l = t & 63;
  const int lo = l & 31, hi = l >> 5;

  // bijective head-clustered XCD swizzle: 432 = 8 xcd * (3 heads * 18 qb)
  const int bid = blockIdx.x;
  const int xcd = bid & 7, jj = bid >> 3;
  const int h = xcd * 3 + jj / 18;
  const int qb = jj % 18;

  const int q0 = qb * 128 + w * 32;
  const size_t head = (size_t)h * SQ_ * DH_;

  // Q as B-operand frags: lane holds Q[q=q0+lo][dh = ks*16 + hi*8 + 0..7]
  bf16x8 qf[8];
  {
    const u16* qp = Qb + head + (size_t)(q0 + lo) * DH_ + hi * 8;
#pragma unroll
    for (int ks = 0; ks < 8; ++ks) qf[ks] = *(const bf16x8*)(qp + ks * 16);
  }
  f32x16 oacc[4];  // O^T: col q = lo, row d = dt*32 + (r&3)+8*(r>>2)+4*hi
#pragma unroll
  for (int dt = 0; dt < 4; ++dt)
#pragma unroll
    for (int i = 0; i < 16; ++i) oacc[dt][i] = 0.f;
  float mrun = -1e30f, lrun = 0.f;

  const u16* kg0 = Kb + head + (size_t)(t >> 4) * DH_ + (t & 15) * 8;
  const u16* vg0 = Vt + head + (size_t)(t >> 3) * SQ_ + (t & 7) * 8;
  const int swz = (lo & 7) << 3;

#define STAGE(buf, kt)                                                   \
  do {                                                                   \
    const u16* kg_ = kg0 + (size_t)(kt) * 64 * DH_;                      \
    _Pragma("unroll")                                                    \
    for (int r_ = 0; r_ < 4; ++r_)                                       \
      gld16(kg_ + (size_t)r_ * 16 * DH_, &Ks[buf][t * 8 + r_ * 2048]);   \
    const u16* vg_ = vg0 + (kt) * 64;                                    \
    _Pragma("unroll")                                                    \
    for (int r_ = 0; r_ < 4; ++r_)                                       \
      gld16(vg_ + (size_t)r_ * 32 * SQ_, &Vs[buf][t * 8 + r_ * 2048]);   \
  } while (0)

  STAGE(0, 0);
  const int nt = SQ_ / 64;  // 36
  for (int kt = 0; kt < nt; ++kt) {
    const int cur = kt & 1;
    if (kt + 1 < nt) {
      STAGE(cur ^ 1, kt + 1);
      asm volatile("s_waitcnt vmcnt(8)" ::: "memory");
    } else {
      asm volatile("s_waitcnt vmcnt(0)" ::: "memory");
    }
    __builtin_amdgcn_s_barrier();

    // S^T = K Q^T: two 32-kpos subtiles
    f32x16 sv0, sv1;
#pragma unroll
    for (int i = 0; i < 16; ++i) { sv0[i] = 0.f; sv1[i] = 0.f; }
#pragma unroll
    for (int ks = 0; ks < 8; ++ks) {
      bf16x8 kf = *(const bf16x8*)&Ks[cur][lo * DH_ + ((ks * 16 + hi * 8) ^ swz)];
      sv0 = __builtin_amdgcn_mfma_f32_32x32x16_bf16(kf, qf[ks], sv0, 0, 0, 0);
    }
#pragma unroll
    for (int ks = 0; ks < 8; ++ks) {
      bf16x8 kf = *(const bf16x8*)&Ks[cur][(32 + lo) * DH_ + ((ks * 16 + hi * 8) ^ swz)];
      sv1 = __builtin_amdgcn_mfma_f32_32x32x16_bf16(kf, qf[ks], sv1, 0, 0, 0);
    }

    // in-register online softmax: lane pair (l, l+32) holds full 64-kpos col
    float tm = sv0[0];
#pragma unroll
    for (int i = 1; i < 16; ++i) tm = fmaxf(tm, sv0[i]);
#pragma unroll
    for (int i = 0; i < 16; ++i) tm = fmaxf(tm, sv1[i]);
    tm = fmaxf(tm, __shfl_xor(tm, 32));
    const float sc = tm * SL_;
    if (!__all(sc - mrun <= 8.0f)) {  // defer-max (T13)
      const float mn = fmaxf(mrun, sc);
      const float scl = __builtin_amdgcn_exp2f(mrun - mn);
      mrun = mn;
      lrun *= scl;
#pragma unroll
      for (int dt = 0; dt < 4; ++dt)
#pragma unroll
        for (int i = 0; i < 16; ++i) oacc[dt][i] *= scl;
    }
    float p0[16], p1[16];
    float rs = 0.f;
#pragma unroll
    for (int i = 0; i < 16; ++i) {
      p0[i] = __builtin_amdgcn_exp2f(fmaf(sv0[i], SL_, -mrun));
      rs += p0[i];
    }
#pragma unroll
    for (int i = 0; i < 16; ++i) {
      p1[i] = __builtin_amdgcn_exp2f(fmaf(sv1[i], SL_, -mrun));
      rs += p1[i];
    }
    rs += __shfl_xor(rs, 32);
    lrun += rs;

    // pack P -> PV B-frags fully in registers (cvt_pk + permlane32_swap)
    unsigned xx[16];
#pragma unroll
    for (int g = 0; g < 8; ++g) xx[g] = cvt_pk_bf16(p0[2 * g], p0[2 * g + 1]);
#pragma unroll
    for (int g = 0; g < 8; ++g) xx[8 + g] = cvt_pk_bf16(p1[2 * g], p1[2 * g + 1]);
#pragma unroll
    for (int b = 0; b < 16; b += 4) {
      asm("v_permlane32_swap_b32 %0, %1" : "+v"(xx[b]), "+v"(xx[b + 2]));
      asm("v_permlane32_swap_b32 %0, %1" : "+v"(xx[b + 1]), "+v"(xx[b + 3]));
    }
    bf16x8 pb[4];
#pragma unroll
    for (int st = 0; st < 4; ++st) {
      union { unsigned u[4]; bf16x8 b; } cv;
      cv.u[0] = xx[4 * st]; cv.u[1] = xx[4 * st + 1];
      cv.u[2] = xx[4 * st + 2]; cv.u[3] = xx[4 * st + 3];
      pb[st] = cv.b;
    }

    // O^T += V^T P^T
#pragma unroll
    for (int dt = 0; dt < 4; ++dt) {
      const int drow = dt * 32 + lo;
#pragma unroll
      for (int st = 0; st < 4; ++st) {
        bf16x8 vf = *(const bf16x8*)&Vs[cur][drow * 64 + ((st * 16 + hi * 8) ^ swz)];
        oacc[dt] = __builtin_amdgcn_mfma_f32_32x32x16_bf16(vf, pb[st], oacc[dt], 0, 0, 0);
      }
    }
    __builtin_amdgcn_s_barrier();
  }
#undef STAGE

  const float rinv = 1.0f / lrun;
  u16* op = attnb + (size_t)(q0 + lo) * DIM_ + h * DH_ + hi * 4;
#pragma unroll
  for (int dt = 0; dt < 4; ++dt)
#pragma unroll
    for (int g = 0; g < 4; ++g) {
      uint2 u;
      u.x = cvt_pk_bf16(oacc[dt][4 * g + 0] * rinv, oacc[dt][4 * g + 1] * rinv);
      u.y = cvt_pk_bf16(oacc[dt][4 * g + 2] * rinv, oacc[dt][4 * g + 3] * rinv);
      *(uint2*)(op + dt * 32 + g * 8) = u;
    }
}

extern "C" void kernel_launch(void* const* d_in, const int* in_sizes, int n_in,
                              void* d_out, int out_size, void* d_ws, size_t ws_size,
                              hipStream_t stream) {
  (void)in_sizes; (void)n_in; (void)out_size; (void)ws_size;
  const float* hidden    = (const float*)d_in[0];
  const float* encoder   = (const float*)d_in[1];
  const float* vid_cos   = (const float*)d_in[2];
  const float* vid_sin   = (const float*)d_in[3];
  const float* txt_cos   = (const float*)d_in[4];
  const float* txt_sin   = (const float*)d_in[5];
  const float* w_qkv     = (const float*)d_in[6];
  const float* b_qkv     = (const float*)d_in[7];
  const float* w_add_qkv = (const float*)d_in[8];
  const float* b_add_qkv = (const float*)d_in[9];
  const float* norm_q_w  = (const float*)d_in[10];
  const float* norm_k_w  = (const float*)d_in[11];
  const float* norm_aq_w = (const float*)d_in[12];
  const float* norm_ak_w = (const float*)d_in[13];
  const float* w_out     = (const float*)d_in[14];
  const float* b_out     = (const float*)d_in[15];
  const float* w_add_out = (const float*)d_in[16];
  const float* b_add_out = (const float*)d_in[17];
  float* out = (float*)d_out;

  char* ws = (char*)d_ws;
  u16* wqkv_t    = (u16*)(ws + 0);            // 9216x3072 bf16
  u16* waddqkv_t = (u16*)(ws + 56623104);
  u16* img_qkv   = (u16*)(ws + 113246208);    // 2048x9216
  u16* txt_qkv   = (u16*)(ws + 150994944);    // 256x9216
  u16* Qb        = (u16*)(ws + 155713536);    // 24x2304x128
  u16* Kb        = (u16*)(ws + 169869312);
  u16* Vt        = (u16*)(ws + 184025088);    // end 198,180,864
  u16* wout_t    = wqkv_t;
  u16* waddout_t = waddqkv_t;
  u16* attnb     = img_qkv;
  u16* hidden_bf = Qb;
  u16* encoder_bf = Kb;

  k_f2b<<<(SIMG_ * DIM_) / 1024, 256, 0, stream>>>(hidden, hidden_bf, SIMG_ * DIM_);
  k_f2b<<<(STXT_ * DIM_) / 1024, 256, 0, stream>>>(encoder, encoder_bf, STXT_ * DIM_);
  k_transpose<<<dim3(NQKV_ / 64, DIM_ / 64), 256, 0, stream>>>(w_qkv, wqkv_t, DIM_, NQKV_);
  k_transpose<<<dim3(NQKV_ / 64, DIM_ / 64), 256, 0, stream>>>(w_add_qkv, waddqkv_t, DIM_, NQKV_);
  k_gemm_bt<false><<<(NQKV_ / 128) * (SIMG_ / 128), 256, 0, stream>>>(hidden_bf, wqkv_t, b_qkv, img_qkv, SIMG_, NQKV_, DIM_);
  k_gemm_bt<false><<<(NQKV_ / 128) * (STXT_ / 128), 256, 0, stream>>>(encoder_bf, waddqkv_t, b_add_qkv, txt_qkv, STXT_, NQKV_, DIM_);
  k_norm_rope<<<(SQ_ * H_) / 4, 256, 0, stream>>>(img_qkv, txt_qkv, vid_cos, vid_sin,
                                                  txt_cos, txt_sin, norm_q_w, norm_k_w,
                                                  norm_aq_w, norm_ak_w, Qb, Kb);
  k_vt<<<dim3(SQ_ / 64, H_), 256, 0, stream>>>(img_qkv, txt_qkv, Vt);
  k_attn<<<(SQ_ / 128) * H_, 256, 0, stream>>>(Qb, Kb, Vt, attnb);
  k_transpose<<<dim3(DIM_ / 64, DIM_ / 64), 256, 0, stream>>>(w_out, wout_t, DIM_, DIM_);
  k_transpose<<<dim3(DIM_ / 64, DIM_ / 64), 256, 0, stream>>>(w_add_out, waddout_t, DIM_, DIM_);
  k_gemm_bt<true><<<(DIM_ / 128) * (SIMG_ / 128), 256, 0, stream>>>(attnb + (size_t)STXT_ * DIM_, wout_t, b_out, out, SIMG_, DIM_, DIM_);
  k_gemm_bt<true><<<(DIM_ / 128) * (STXT_ / 128), 256, 0, stream>>>(attnb, waddout_t, b_add_out, out + (size_t)SIMG_ * DIM_, STXT_, DIM_, DIM_);
}